// Round 2
// baseline (17671.243 us; speedup 1.0000x reference)
//
#include <hip/hip_runtime.h>
#include <hip/hip_bf16.h>
#include <hip/hip_fp16.h>

// ============================================================================
// 2-layer LSTM (TF BasicLSTMCell, forget_bias=1), B=32, T=2048, D=H=256.
// Runtime dtype detection (fp32 vs bf16) -> single f16-staged pipeline:
//   detect   : sniff x's dtype from uint16 exponent statistics -> flag in ws
//   prep     : BT (x-part W^T, f16), Wp (packed f16 recurrent W), biases, states
//   conv_x   : layer-1 input chunk -> f16 chunk-local [32*Tc][256]
//   gemm_xw  : G = A(f16) @ BT^T + bias   (MFMA 16x16x32 f16, reg-direct)
//   lstm_recur: 32 WGs (1/batch), sequential over Tc, v_dot2_f32_f16
// ============================================================================

typedef __attribute__((ext_vector_type(8))) _Float16 f16x8;
typedef __attribute__((ext_vector_type(4))) float f32x4;
typedef _Float16 half_t;
typedef __attribute__((ext_vector_type(2))) _Float16 h2v;

static __device__ __forceinline__ float bf2f(unsigned short u) {
  union { unsigned u; float f; } v; v.u = ((unsigned)u) << 16; return v.f;
}
static __device__ __forceinline__ unsigned short f2bf(float f) {
  union { float f; unsigned u; } v; v.f = f;
  unsigned r = v.u + 0x7fffu + ((v.u >> 16) & 1u);
  return (unsigned short)(r >> 16);
}
// load element i of a W/b/x tensor whose dtype is fp32 (flag=1) or bf16 (flag=0)
static __device__ __forceinline__ float ldw(const void* p, long i, int fp32) {
  return fp32 ? ((const float*)p)[i] : bf2f(((const unsigned short*)p)[i]);
}
static __device__ __forceinline__ float rcpf(float x) { return __builtin_amdgcn_rcpf(x); }
static __device__ __forceinline__ float sigm(float x) { return rcpf(1.f + __expf(-x)); }
static __device__ __forceinline__ float tanh_(float x) {
  float e = __expf(-2.f * fabsf(x));
  float t = (1.f - e) * rcpf(1.f + e);
  return copysignf(t, x);
}
static __device__ __forceinline__ float fdot2(h2v a, h2v b, float c) {
#if __has_builtin(__builtin_amdgcn_fdot2)
  return __builtin_amdgcn_fdot2(a, b, c, false);
#else
  return c + (float)a.x * (float)b.x + (float)a.y * (float)b.y;
#endif
}

// ----------------------------------------------------------------------------
// detect: bf16 N(0,1) data never has exponent bits >= 192; fp32 buffers read
// as uint16 have uniform-random low halves (~25% hit). flag=1 -> fp32.
// ----------------------------------------------------------------------------
__global__ __launch_bounds__(256) void detect(const unsigned short* __restrict__ x,
                                              int* __restrict__ flag) {
  __shared__ int cnt;
  if (threadIdx.x == 0) cnt = 0;
  __syncthreads();
  int c = 0;
#pragma unroll
  for (int i = 0; i < 8; ++i) {
    unsigned short u = x[threadIdx.x * 8 + i];
    c += (((u >> 7) & 0xFF) >= 192) ? 1 : 0;
  }
  atomicAdd(&cnt, c);
  __syncthreads();
  if (threadIdx.x == 0) *flag = (cnt > 16) ? 1 : 0;
}

// ----------------------------------------------------------------------------
// prep: task 0/1: BT (f16 [1024][256] = W[0:256,:]^T); task 2/3: Wp f16 pack
// [(k8*4+g)*256+j]*8+kk = W[256+k8*8+kk][g*256+j]; task 4: biases + zero states.
// ----------------------------------------------------------------------------
__global__ __launch_bounds__(256) void prep(
    const void* __restrict__ W0, const void* __restrict__ W1,
    const void* __restrict__ b0, const void* __restrict__ b1,
    const int* __restrict__ flag,
    half_t* __restrict__ BT0, half_t* __restrict__ BT1,
    half_t* __restrict__ Wp0, half_t* __restrict__ Wp1,
    float* __restrict__ bias0, float* __restrict__ bias1,
    float* __restrict__ c1, float* __restrict__ c2,
    half_t* __restrict__ h1s, half_t* __restrict__ h2s)
{
  const int fp32 = *flag;
  int id = blockIdx.x * 256 + threadIdx.x;   // 0..262143
  int task = blockIdx.y;
  if (task <= 1) {
    const void* W = task ? W1 : W0;
    half_t* BT = task ? BT1 : BT0;
    int n = id >> 8, k = id & 255;
    BT[n * 256 + k] = (half_t)ldw(W, k * 1024 + n, fp32);
  } else if (task <= 3) {
    const void* W = (task == 3) ? W1 : W0;
    half_t* Wp = (task == 3) ? Wp1 : Wp0;
    int kk = id & 7;
    int j  = (id >> 3) & 255;
    int g  = (id >> 11) & 3;
    int k8 = id >> 13;
    int k  = k8 * 8 + kk;
    Wp[id] = (half_t)ldw(W, (256 + k) * 1024 + g * 256 + j, fp32);
  } else {
    if (id < 1024)        bias0[id] = ldw(b0, id, fp32);
    else if (id < 2048)   bias1[id - 1024] = ldw(b1, id - 1024, fp32);
    else if (id < 10240)  c1[id - 2048] = 0.f;
    else if (id < 18432)  c2[id - 10240] = 0.f;
    else if (id < 26624)  h1s[id - 18432] = (half_t)0.f;
    else if (id < 34816)  h2s[id - 26624] = (half_t)0.f;
  }
}

// ----------------------------------------------------------------------------
// conv_x: gather layer-1 input chunk into f16 chunk-local [32*Tc][256]
// ----------------------------------------------------------------------------
__global__ __launch_bounds__(256) void conv_x(
    const void* __restrict__ x, const int* __restrict__ flag,
    half_t* __restrict__ xf, int t0, int tcShift)
{
  const int fp32 = *flag;
  int gid = blockIdx.x * 256 + threadIdx.x;       // 0 .. 32*Tc*256-1
  int b = gid >> (tcShift + 8);
  int r = gid & ((1 << (tcShift + 8)) - 1);
  long src = (long)b * (2048 * 256) + (long)t0 * 256 + r;
  xf[gid] = (half_t)ldw(x, src, fp32);
}

// ----------------------------------------------------------------------------
// gemm_xw: G[row][1024](f16) = A[row][256](f16) @ BT^T + bias
// A chunk-local [32*Tc][256]; 128x128 tile, 4 waves (2x2), K=256 in registers.
// ----------------------------------------------------------------------------
__global__ __launch_bounds__(256) void gemm_xw(
    const half_t* __restrict__ A,
    const half_t* __restrict__ BT,
    const float* __restrict__ bias,
    half_t* __restrict__ G)
{
  const int lane = threadIdx.x & 63;
  const int wave = threadIdx.x >> 6;
  const int wm = wave >> 1, wn = wave & 1;
  const int m0 = blockIdx.x * 128 + wm * 64;
  const int n0 = blockIdx.y * 128 + wn * 64;
  const int lm = lane & 15;   // row/col within 16
  const int q  = lane >> 4;   // quad: A/B k = q*8+j ; C row = q*4+r

  f32x4 acc[4][4] = {};
  long aoff[4], boff[4];
#pragma unroll
  for (int fm = 0; fm < 4; ++fm)
    aoff[fm] = (long)(m0 + fm * 16 + lm) * 256 + q * 8;
#pragma unroll
  for (int fn = 0; fn < 4; ++fn)
    boff[fn] = (long)(n0 + fn * 16 + lm) * 256 + q * 8;

#pragma unroll
  for (int kt = 0; kt < 8; ++kt) {
    f16x8 aF[4], bF[4];
#pragma unroll
    for (int fm = 0; fm < 4; ++fm)
      aF[fm] = *(const f16x8*)(A + aoff[fm] + kt * 32);
#pragma unroll
    for (int fn = 0; fn < 4; ++fn)
      bF[fn] = *(const f16x8*)(BT + boff[fn] + kt * 32);
#pragma unroll
    for (int fm = 0; fm < 4; ++fm)
#pragma unroll
      for (int fn = 0; fn < 4; ++fn)
        acc[fm][fn] = __builtin_amdgcn_mfma_f32_16x16x32_f16(
            aF[fm], bF[fn], acc[fm][fn], 0, 0, 0);
  }
  // C/D: col = lane&15, row = (lane>>4)*4 + r   [m89; dtype-independent m121-128]
#pragma unroll
  for (int fm = 0; fm < 4; ++fm) {
#pragma unroll
    for (int fn = 0; fn < 4; ++fn) {
      int col = n0 + fn * 16 + lm;
      float bs = bias[col];
#pragma unroll
      for (int r = 0; r < 4; ++r) {
        int row = m0 + fm * 16 + q * 4 + r;
        G[row * 1024 + col] = (half_t)(acc[fm][fn][r] + bs);
      }
    }
  }
}

// ----------------------------------------------------------------------------
// lstm_recur: one WG per batch element. j = tid&255 owns h-index j (its 4 gate
// columns, c[j] in register); tid>>8 splits K (0..127 / 128..255).
// finalOut=0: write f16 chunk-local h1c; finalOut=1: write d_out (flag dtype).
// ----------------------------------------------------------------------------
__global__ __launch_bounds__(512) void lstm_recur(
    const half_t* __restrict__ G,        // [32*Tc][1024] chunk-local (bias incl.)
    const uint4* __restrict__ Wp,        // packed f16 recurrent weights
    float* __restrict__ cstate,          // [32][256] fp32
    half_t* __restrict__ hstate,         // [32][256] f16
    void* __restrict__ hout,
    const int* __restrict__ flag,
    int Tc, int outStride, int outBase, int finalOut)
{
  const int fp32 = *flag;
  const int b = blockIdx.x;
  const int tid = threadIdx.x;
  const int j = tid & 255;
  const int hi = tid >> 8;               // 0: k 0..127, 1: k 128..255 (+G loads)

  __shared__ __align__(16) half_t hsh[2][256];
  __shared__ float part[4][256];

  float c = 0.f;
  if (!hi) {
    c = cstate[b * 256 + j];
    hsh[0][j] = hstate[b * 256 + j];
  }
  __syncthreads();

  const half_t* Gb = G + (long)b * Tc * 1024;
  const long outB = (long)b * outStride;
  int cur = 0;

  for (int tl = 0; tl < Tc; ++tl) {
    float g4[4];
    if (hi) {
#pragma unroll
      for (int g = 0; g < 4; ++g)
        g4[g] = (float)Gb[tl * 1024 + g * 256 + j];
    }
    float accg[4] = {0.f, 0.f, 0.f, 0.f};
    const int k8base = hi ? 16 : 0;
#pragma unroll 4
    for (int k8 = 0; k8 < 16; ++k8) {
      int kk = k8base + k8;
      union { float4 f; h2v h[4]; } hu;
      hu.f = *(const float4*)&hsh[cur][(kk & 31) * 8];
#pragma unroll
      for (int g = 0; g < 4; ++g) {
        union { uint4 u; h2v h[4]; } wu;
        wu.u = Wp[(kk * 4 + g) * 256 + j];          // coalesced 16B
        float a = accg[g];
        a = fdot2(hu.h[0], wu.h[0], a);
        a = fdot2(hu.h[1], wu.h[1], a);
        a = fdot2(hu.h[2], wu.h[2], a);
        a = fdot2(hu.h[3], wu.h[3], a);
        accg[g] = a;
      }
    }
    if (hi) {
#pragma unroll
      for (int g = 0; g < 4; ++g) part[g][j] = accg[g] + g4[g];
    }
    __syncthreads();                     // partials ready / all reads of hsh done
    if (!hi) {
      float gi = accg[0] + part[0][j];
      float gj = accg[1] + part[1][j];
      float gf = accg[2] + part[2][j];
      float go = accg[3] + part[3][j];
      float cn = c * sigm(gf + 1.f) + sigm(gi) * tanh_(gj);
      c = cn;
      float h = tanh_(cn) * sigm(go);
      hsh[cur ^ 1][j] = (half_t)h;
      long idx = outB + (long)(outBase + tl) * 256 + j;
      if (finalOut) {
        if (fp32) ((float*)hout)[idx] = h;
        else      ((unsigned short*)hout)[idx] = f2bf(h);
      } else {
        ((half_t*)hout)[idx] = (half_t)h;
      }
    }
    __syncthreads();                     // h_new visible for next step
    cur ^= 1;
  }
  if (!hi) {
    cstate[b * 256 + j] = c;
    hstate[b * 256 + j] = hsh[cur][j];
  }
}

// ----------------------------------------------------------------------------
extern "C" void kernel_launch(void* const* d_in, const int* in_sizes, int n_in,
                              void* d_out, int out_size, void* d_ws, size_t ws_size,
                              hipStream_t stream) {
  const void* x  = d_in[0];   // [32][2048][256]
  const void* W0 = d_in[1];   // [512][1024]
  const void* b0 = d_in[2];   // [1024]
  const void* W1 = d_in[3];   // [512][1024]
  const void* b1 = d_in[4];   // [1024]

  // ws: xf16(16384*Tc) G(65536*Tc) h1c(16384*Tc) BT0 BT1 Wp0 Wp1 (524288 ea)
  //     bias0 bias1 (4096) c1 c2 (32768) h1s h2s (16384) flag(256)
  const long FIXED = 4L * 524288 + 2L * 4096 + 2L * 32768 + 2L * 16384 + 256;
  int tcShift = 11;                                  // Tc = 2048 .. 32
  while (tcShift > 5 &&
         (98304L * (1L << tcShift) + FIXED) > (long)ws_size) tcShift--;
  const int Tc = 1 << tcShift;
  const int nCh = 2048 >> tcShift;

  char* p = (char*)d_ws;
  half_t* xf   = (half_t*)p;  p += (size_t)16384 * Tc;
  half_t* G    = (half_t*)p;  p += (size_t)65536 * Tc;
  half_t* h1c  = (half_t*)p;  p += (size_t)16384 * Tc;
  half_t* BT0  = (half_t*)p;  p += 524288;
  half_t* BT1  = (half_t*)p;  p += 524288;
  half_t* Wp0  = (half_t*)p;  p += 524288;
  half_t* Wp1  = (half_t*)p;  p += 524288;
  float* bias0 = (float*)p;   p += 4096;
  float* bias1 = (float*)p;   p += 4096;
  float* c1    = (float*)p;   p += 32768;
  float* c2    = (float*)p;   p += 32768;
  half_t* h1s  = (half_t*)p;  p += 16384;
  half_t* h2s  = (half_t*)p;  p += 16384;
  int* flag    = (int*)p;     p += 256;

  detect<<<1, 256, 0, stream>>>((const unsigned short*)x, flag);
  prep<<<dim3(1024, 5), 256, 0, stream>>>(W0, W1, b0, b1, flag,
                                          BT0, BT1, Wp0, Wp1,
                                          bias0, bias1, c1, c2, h1s, h2s);

  const dim3 ggrid((32 * Tc) / 128, 8);
  for (int ch = 0; ch < nCh; ++ch) {
    int t0 = ch << tcShift;
    // layer 1
    conv_x<<<32 * Tc, 256, 0, stream>>>(x, flag, xf, t0, tcShift);
    gemm_xw<<<ggrid, 256, 0, stream>>>(xf, BT0, bias0, G);
    lstm_recur<<<32, 512, 0, stream>>>(G, (const uint4*)Wp0, c1, h1s, h1c,
                                       flag, Tc, Tc * 256, 0, 0);
    // layer 2
    gemm_xw<<<ggrid, 256, 0, stream>>>(h1c, BT1, bias1, G);
    lstm_recur<<<32, 512, 0, stream>>>(G, (const uint4*)Wp1, c2, h2s, d_out,
                                       flag, Tc, 2048 * 256, t0, 1);
  }
}